// Round 3
// baseline (63.360 us; speedup 1.0000x reference)
//
#include <hip/hip_runtime.h>
#include <hip/hip_bf16.h>

// Problem constants
#define N_NODES 100000
#define S_SAMP  2048
#define E_EDGE  131072
#define NB      391            // ceil(N/256); 391*256 = 100096
#define PB      512            // K3 blocks: 4 pair rows each; 512*256 == E exactly

// Workspace layout (float offsets)
#define SPA_OFF     0
#define CNT_U32     8          // u32 index into W for the arrival counter
#define CS_PART_OFF 64                       // NB*8 = 3128
#define M2P_OFF     (64 + 3200)              // 8*64 = 512
#define PART_OFF    (M2P_OFF + 512)          // PB = 512
#define BS_OFF      (PART_OFF + 512)         // 2048
#define MS_OFF      (BS_OFF + 2048)          // S*8 = 16384
#define ZT_OFF      (MS_OFF + 16384)         // N*8 = 800000
#define VT_OFF      (ZT_OFF + 800000)        // N*8 = 800000
// total ~1.63M floats = 6.5 MB

// ---------------------------------------------------------------------------
// K1: zt = softmax(Zp) columns; colsum partials; M2raw partials (blocks 0..7,
//     recomputing sample columns straight from Zp); Bs; sp_a; counter reset.
// ---------------------------------------------------------------------------
__global__ __launch_bounds__(256) void k1(const float* __restrict__ beta,
                                          const float* __restrict__ a,
                                          const float* __restrict__ Zp,
                                          const float* __restrict__ Gp,
                                          const int* __restrict__ sidx,
                                          float* __restrict__ W) {
    const int tid = threadIdx.x, bid = blockIdx.x;
    const int n = bid * 256 + tid;
    const int lane = tid & 63, wave = tid >> 6;
    __shared__ float sred[4][64];

    float part[8] = {0,0,0,0,0,0,0,0};
    if (n < N_NODES) {
        float zv[8]; float mx = -1e30f;
        #pragma unroll
        for (int k = 0; k < 8; ++k) {
            zv[k] = Zp[(size_t)k * N_NODES + n];
            mx = fmaxf(mx, zv[k]);
        }
        float den = 0.f;
        #pragma unroll
        for (int k = 0; k < 8; ++k) { zv[k] = __expf(zv[k] - mx); den += zv[k]; }
        float inv = 1.f / den;
        float4 g0 = *(const float4*)&Gp[(size_t)n * 8];
        float4 g1 = *(const float4*)&Gp[(size_t)n * 8 + 4];
        float g[8] = {g0.x,g0.y,g0.z,g0.w,g1.x,g1.y,g1.z,g1.w};
        float zt[8];
        #pragma unroll
        for (int k = 0; k < 8; ++k) {
            float z = zv[k] * inv;
            zt[k] = z;
            part[k] = z / (1.f + __expf(-g[k]));
        }
        *(float4*)&W[ZT_OFF + (size_t)n * 8]     = make_float4(zt[0],zt[1],zt[2],zt[3]);
        *(float4*)&W[ZT_OFF + (size_t)n * 8 + 4] = make_float4(zt[4],zt[5],zt[6],zt[7]);
    }
    #pragma unroll
    for (int k = 0; k < 8; ++k) {
        float x = part[k];
        #pragma unroll
        for (int off = 32; off; off >>= 1) x += __shfl_down(x, off, 64);
        if (lane == 0) sred[wave][k] = x;
    }
    __syncthreads();
    if (tid < 8)
        W[CS_PART_OFF + bid * 8 + tid] =
            sred[0][tid] + sred[1][tid] + sred[2][tid] + sred[3][tid];
    if (n == 0) {
        float av = a[0];
        W[SPA_OFF] = fmaxf(av, 0.f) + log1pf(__expf(-fabsf(av)));  // softplus
        ((unsigned*)W)[CNT_U32] = 0u;                              // arrival counter
    }

    // ---- sample blocks: M2raw partials + Bs (independent of colsum/zt) ----
    if (bid < 8) {
        int s = bid * 256 + tid;            // exactly S_SAMP threads
        int idx = sidx[s];
        float zv[8]; float mx = -1e30f;
        #pragma unroll
        for (int k = 0; k < 8; ++k) {
            zv[k] = Zp[(size_t)k * N_NODES + idx];
            mx = fmaxf(mx, zv[k]);
        }
        float den = 0.f;
        #pragma unroll
        for (int k = 0; k < 8; ++k) { zv[k] = __expf(zv[k] - mx); den += zv[k]; }
        float inv = 1.f / den;
        float4 g0 = *(const float4*)&Gp[(size_t)idx * 8];
        float4 g1 = *(const float4*)&Gp[(size_t)idx * 8 + 4];
        float g[8] = {g0.x,g0.y,g0.z,g0.w,g1.x,g1.y,g1.z,g1.w};
        float z[8], w8[8];
        #pragma unroll
        for (int k = 0; k < 8; ++k) {
            z[k]  = zv[k] * inv;
            w8[k] = z[k] / (1.f + __expf(-g[k]));
        }
        W[BS_OFF + s] = beta[idx];

        __syncthreads();                    // guard sred reuse
        #pragma unroll
        for (int k = 0; k < 8; ++k) {
            #pragma unroll
            for (int j = 0; j < 8; ++j) {
                float x = z[k] * w8[j];
                #pragma unroll
                for (int off = 32; off; off >>= 1) x += __shfl_down(x, off, 64);
                if (lane == 0) sred[wave][k * 8 + j] = x;
            }
        }
        __syncthreads();
        if (tid < 64)
            W[M2P_OFF + bid * 64 + tid] =
                sred[0][tid] + sred[1][tid] + sred[2][tid] + sred[3][tid];
    }
}

// ---------------------------------------------------------------------------
// K2: every block re-reduces colsum+M2raw partials -> M2 in LDS;
//     vt[n] = M2 @ zt[n] for all n; blocks 0..7: Ms[s] = M2 @ zt[idx_s].
// ---------------------------------------------------------------------------
__global__ __launch_bounds__(256) void k2(const int* __restrict__ sidx,
                                          float* __restrict__ W) {
    const int tid = threadIdx.x, bid = blockIdx.x;
    __shared__ float sflat[256];
    __shared__ float sinv8[8];
    __shared__ float sM2[64];

    {   // colsum reduce: 32 groups of 8
        int k = tid & 7, g = tid >> 3;
        float s = 0.f;
        for (int b = g; b < NB; b += 32) s += W[CS_PART_OFF + b * 8 + k];
        sflat[tid] = s;
    }
    __syncthreads();
    if (tid < 8) {
        float s = 0.f;
        #pragma unroll
        for (int g = 0; g < 32; ++g) s += sflat[g * 8 + tid];
        sinv8[tid] = 1.f / s;
    }
    __syncthreads();
    if (tid < 64) {
        float m = 0.f;
        #pragma unroll
        for (int b = 0; b < 8; ++b) m += W[M2P_OFF + b * 64 + tid];
        sM2[tid] = m * sinv8[tid & 7];      // M2[k][j] = M2raw[k][j]/colsum[j]
    }
    __syncthreads();

    int n = bid * 256 + tid;
    if (n < N_NODES) {
        float4 z0 = *(const float4*)&W[ZT_OFF + (size_t)n * 8];
        float4 z1 = *(const float4*)&W[ZT_OFF + (size_t)n * 8 + 4];
        float z[8] = {z0.x,z0.y,z0.z,z0.w,z1.x,z1.y,z1.z,z1.w};
        float v[8];
        #pragma unroll
        for (int k = 0; k < 8; ++k) {
            float acc = 0.f;
            #pragma unroll
            for (int j = 0; j < 8; ++j) acc += sM2[k * 8 + j] * z[j];
            v[k] = acc;
        }
        *(float4*)&W[VT_OFF + (size_t)n * 8]     = make_float4(v[0],v[1],v[2],v[3]);
        *(float4*)&W[VT_OFF + (size_t)n * 8 + 4] = make_float4(v[4],v[5],v[6],v[7]);
    }
    if (bid < 8) {                          // Ms from zt gather (global, from K1)
        int s = bid * 256 + tid;
        int idx = sidx[s];
        float4 z0 = *(const float4*)&W[ZT_OFF + (size_t)idx * 8];
        float4 z1 = *(const float4*)&W[ZT_OFF + (size_t)idx * 8 + 4];
        float z[8] = {z0.x,z0.y,z0.z,z0.w,z1.x,z1.y,z1.z,z1.w};
        float v[8];
        #pragma unroll
        for (int k = 0; k < 8; ++k) {
            float acc = 0.f;
            #pragma unroll
            for (int j = 0; j < 8; ++j) acc += sM2[k * 8 + j] * z[j];
            v[k] = acc;
        }
        *(float4*)&W[MS_OFF + (size_t)s * 8]     = make_float4(v[0],v[1],v[2],v[3]);
        *(float4*)&W[MS_OFF + (size_t)s * 8 + 4] = make_float4(v[4],v[5],v[6],v[7]);
    }
}

// ---------------------------------------------------------------------------
// K3: pair rows (4/block) + sparse edges (1/thread, 512*256==E) ->
//     per-block partial; deterministic last-block final reduce -> out.
// ---------------------------------------------------------------------------
__global__ __launch_bounds__(256) void k3(const float* __restrict__ beta,
                                          const int* __restrict__ si,
                                          const int* __restrict__ sj,
                                          float* __restrict__ out,
                                          float* __restrict__ W) {
    const int tid = threadIdx.x, bid = blockIdx.x;
    const int lane = tid & 63, wave = tid >> 6;
    const int gtid = bid * 256 + tid;
    const float spa = W[SPA_OFF];
    const float* Ms = W + MS_OFF;
    const float* Bs = W + BS_OFF;

    float accp = 0.f;
    #pragma unroll
    for (int r = 0; r < 4; ++r) {
        int srow = bid * 4 + r;
        float4 m0 = *(const float4*)&Ms[(size_t)srow * 8];
        float4 m1 = *(const float4*)&Ms[(size_t)srow * 8 + 4];
        float bsv = Bs[srow];
        for (int t = tid; t < S_SAMP; t += 256) {
            float4 a0 = *(const float4*)&Ms[(size_t)t * 8];
            float4 a1 = *(const float4*)&Ms[(size_t)t * 8 + 4];
            float d, ss;
            d = m0.x - a0.x + 1e-6f; ss  = d * d;
            d = m0.y - a0.y + 1e-6f; ss += d * d;
            d = m0.z - a0.z + 1e-6f; ss += d * d;
            d = m0.w - a0.w + 1e-6f; ss += d * d;
            d = m1.x - a1.x + 1e-6f; ss += d * d;
            d = m1.y - a1.y + 1e-6f; ss += d * d;
            d = m1.z - a1.z + 1e-6f; ss += d * d;
            d = m1.w - a1.w + 1e-6f; ss += d * d;
            float val = __expf(bsv + Bs[t] - spa * sqrtf(ss));
            if (t != srow) accp += val;
        }
    }
    float accs;
    {
        int i = si[gtid], j = sj[gtid];
        const float* vt = W + VT_OFF;
        float4 vi0 = *(const float4*)&vt[(size_t)i * 8];
        float4 vi1 = *(const float4*)&vt[(size_t)i * 8 + 4];
        float4 vj0 = *(const float4*)&vt[(size_t)j * 8];
        float4 vj1 = *(const float4*)&vt[(size_t)j * 8 + 4];
        float d, ss;
        d = vi0.x - vj0.x + 1e-6f; ss  = d * d;
        d = vi0.y - vj0.y + 1e-6f; ss += d * d;
        d = vi0.z - vj0.z + 1e-6f; ss += d * d;
        d = vi0.w - vj0.w + 1e-6f; ss += d * d;
        d = vi1.x - vj1.x + 1e-6f; ss += d * d;
        d = vi1.y - vj1.y + 1e-6f; ss += d * d;
        d = vi1.z - vj1.z + 1e-6f; ss += d * d;
        d = vi1.w - vj1.w + 1e-6f; ss += d * d;
        accs = beta[i] + beta[j] - spa * sqrtf(ss);
    }

    float part = accs - 0.5f * 7.38905609893065f * accp;   // e^2
    __shared__ float sw[4];
    #pragma unroll
    for (int off = 32; off; off >>= 1) part += __shfl_down(part, off, 64);
    if (lane == 0) sw[wave] = part;
    __syncthreads();
    if (tid == 0) W[PART_OFF + bid] = sw[0] + sw[1] + sw[2] + sw[3];

    // last-block deterministic final reduce
    __shared__ int sLast;
    if (tid == 0) {
        __threadfence();
        unsigned old = atomicAdd(&((unsigned*)W)[CNT_U32], 1u);
        sLast = (old == PB - 1);
    }
    __syncthreads();
    if (sLast) {
        __threadfence();
        __shared__ double sd[256];
        double s = 0.0;
        for (int i = tid; i < PB; i += 256) s += (double)W[PART_OFF + i];
        sd[tid] = s;
        __syncthreads();
        for (int k = 128; k > 0; k >>= 1) {
            if (tid < k) sd[tid] += sd[tid + k];
            __syncthreads();
        }
        if (tid == 0) out[0] = (float)sd[0];
    }
}

extern "C" void kernel_launch(void* const* d_in, const int* in_sizes, int n_in,
                              void* d_out, int out_size, void* d_ws, size_t ws_size,
                              hipStream_t stream) {
    const float* beta       = (const float*)d_in[0];
    const float* a          = (const float*)d_in[1];
    const float* Zp         = (const float*)d_in[2];
    const float* Gp         = (const float*)d_in[3];
    const int*   sample_idx = (const int*)d_in[4];
    const int*   sparse_i   = (const int*)d_in[5];
    const int*   sparse_j   = (const int*)d_in[6];
    float* out = (float*)d_out;
    float* W   = (float*)d_ws;

    k1<<<dim3(NB), dim3(256), 0, stream>>>(beta, a, Zp, Gp, sample_idx, W);
    k2<<<dim3(NB), dim3(256), 0, stream>>>(sample_idx, W);
    k3<<<dim3(PB), dim3(256), 0, stream>>>(beta, sparse_i, sparse_j, out, W);
}